// Round 2
// baseline (273.731 us; speedup 1.0000x reference)
//
#include <hip/hip_runtime.h>
#include <hip/hip_bf16.h>

#define B_ 4
#define L_ 1024
#define H_ 12
#define DK_ 64
#define FEA_ 768
#define MASKV (-32767.0f)

typedef __attribute__((ext_vector_type(8))) short bf16x8;
typedef __attribute__((ext_vector_type(4))) short s16x4;
typedef __attribute__((ext_vector_type(4))) float f32x4;

__device__ inline short f2bf(float x) {
  union { float f; unsigned u; } v; v.f = x;
  unsigned r = v.u + 0x7fffu + ((v.u >> 16) & 1u);  // RNE
  return (short)(r >> 16);
}

// ---------------------------------------------------------------------------
// QKV projection: out[m][n] = sum_k X[m][k] * W[n][k] + b[n]
// M=4096, N=768, K=768. 128x128 tile, BK=64, 4 waves (2x2), bf16 MFMA.
// Q,K stored [b][h][l][d] bf16; V stored transposed [b][h][d][l] bf16.
// ---------------------------------------------------------------------------
__global__ __launch_bounds__(256) void k_proj(
    const float* __restrict__ qx, const float* __restrict__ kx,
    const float* __restrict__ vx,
    const float* __restrict__ Wq, const float* __restrict__ bq,
    const float* __restrict__ Wk, const float* __restrict__ bk,
    const float* __restrict__ Wv, const float* __restrict__ bv,
    unsigned short* __restrict__ Qb, unsigned short* __restrict__ Kb,
    unsigned short* __restrict__ Vt)
{
  __shared__ short lA[128 * 64];
  __shared__ short lB[128 * 64];

  const int which = blockIdx.z;
  const float* __restrict__ A    = (which == 0) ? qx : (which == 1) ? kx : vx;
  const float* __restrict__ W    = (which == 0) ? Wq : (which == 1) ? Wk : Wv;
  const float* __restrict__ bias = (which == 0) ? bq : (which == 1) ? bk : bv;

  const int tid = threadIdx.x;
  const int lane = tid & 63;
  const int wid = tid >> 6;
  const int wr = wid >> 1, wc = wid & 1;
  const int m0 = blockIdx.x * 128;
  const int n0 = blockIdx.y * 128;
  const int g = lane >> 4, qc = lane & 15;

  f32x4 acc[4][4];
#pragma unroll
  for (int i = 0; i < 4; i++)
#pragma unroll
    for (int j = 0; j < 4; j++) acc[i][j] = f32x4{0.f, 0.f, 0.f, 0.f};

  for (int kt = 0; kt < FEA_; kt += 64) {
#pragma unroll
    for (int i = 0; i < 4; i++) {
      int gg = i * 256 + tid;          // 1024 chunks of 8 elems
      int row = gg >> 3, c = gg & 7;
      const float4* pa = (const float4*)(A + (size_t)(m0 + row) * FEA_ + kt + c * 8);
      float4 a0 = pa[0], a1 = pa[1];
      bf16x8 av;
      av[0] = f2bf(a0.x); av[1] = f2bf(a0.y); av[2] = f2bf(a0.z); av[3] = f2bf(a0.w);
      av[4] = f2bf(a1.x); av[5] = f2bf(a1.y); av[6] = f2bf(a1.z); av[7] = f2bf(a1.w);
      *(bf16x8*)&lA[row * 64 + ((c ^ (row & 7)) << 3)] = av;
      const float4* pb = (const float4*)(W + (size_t)(n0 + row) * FEA_ + kt + c * 8);
      float4 b0 = pb[0], b1 = pb[1];
      bf16x8 bw;
      bw[0] = f2bf(b0.x); bw[1] = f2bf(b0.y); bw[2] = f2bf(b0.z); bw[3] = f2bf(b0.w);
      bw[4] = f2bf(b1.x); bw[5] = f2bf(b1.y); bw[6] = f2bf(b1.z); bw[7] = f2bf(b1.w);
      *(bf16x8*)&lB[row * 64 + ((c ^ (row & 7)) << 3)] = bw;
    }
    __syncthreads();
#pragma unroll
    for (int s = 0; s < 2; s++) {
      bf16x8 af[4], bfr[4];
#pragma unroll
      for (int i = 0; i < 4; i++) {
        int ar = wr * 64 + i * 16 + qc;
        af[i] = *(const bf16x8*)&lA[ar * 64 + (((s * 4 + g) ^ (ar & 7)) << 3)];
        int br = wc * 64 + i * 16 + qc;
        bfr[i] = *(const bf16x8*)&lB[br * 64 + (((s * 4 + g) ^ (br & 7)) << 3)];
      }
#pragma unroll
      for (int i = 0; i < 4; i++)
#pragma unroll
        for (int j = 0; j < 4; j++)
          acc[i][j] = __builtin_amdgcn_mfma_f32_16x16x32_bf16(af[i], bfr[j], acc[i][j], 0, 0, 0);
    }
    __syncthreads();
  }

  const int cn0 = n0 + wc * 64;
  float bv4[4];
#pragma unroll
  for (int j = 0; j < 4; j++) bv4[j] = bias[cn0 + j * 16 + qc];

#pragma unroll
  for (int i = 0; i < 4; i++) {
    int m = m0 + wr * 64 + i * 16 + g * 4;
    int bb = m >> 10;
    int l = m & 1023;
#pragma unroll
    for (int j = 0; j < 4; j++) {
      int n = cn0 + j * 16 + qc;
      int hh = n >> 6, d = n & 63;
#pragma unroll
      for (int r = 0; r < 4; r++) {
        unsigned short v = (unsigned short)f2bf(acc[i][j][r] + bv4[j]);
        if (which == 2) {
          Vt[(((size_t)bb * H_ + hh) * DK_ + d) * L_ + (l + r)] = v;
        } else if (which == 0) {
          Qb[(((size_t)bb * H_ + hh) * L_ + (l + r)) * DK_ + d] = v;
        } else {
          Kb[(((size_t)bb * H_ + hh) * L_ + (l + r)) * DK_ + d] = v;
        }
      }
    }
  }
}

// ---------------------------------------------------------------------------
// Fused attention v2: barrier-free. Per block (qt, h, b), 4 waves, each wave
// owns 16 q rows independently. K/V fragments read DIRECTLY from L2 (K/V per
// (b,h) = 256 KB, reused by 16 blocks -> L2-resident; no LDS staging, no
// __syncthreads). preScores stream register-prefetched one tile ahead.
// P bounced through wave-private swizzled LDS (same-wave ds visibility only).
// ---------------------------------------------------------------------------
__global__ __launch_bounds__(256, 3) void k_attn(
    const unsigned short* __restrict__ Qb, const unsigned short* __restrict__ Kb,
    const unsigned short* __restrict__ Vt,
    const float* __restrict__ preScores, const int* __restrict__ maskPAD,
    float* __restrict__ scoresOut, unsigned short* __restrict__ zp)
{
  __shared__ short lP[4][16 * 64];

  const int tid = threadIdx.x, lane = tid & 63, wid = tid >> 6;
  const int qt = blockIdx.x, h = blockIdx.y, b = blockIdx.z;
  const int q0 = qt * 64;
  const int g = lane >> 4, qr = lane & 15;
  const int qrow = q0 + wid * 16 + qr;    // global q row in [0,1024)

  const size_t bh = (size_t)b * H_ + h;
  const unsigned short* __restrict__ Kbh = Kb + bh * L_ * DK_;
  const unsigned short* __restrict__ Vbh = Vt + bh * DK_ * L_;

  bf16x8 qf[2];
#pragma unroll
  for (int s = 0; s < 2; s++)
    qf[s] = *(const bf16x8*)(Qb + (bh * L_ + qrow) * DK_ + s * 32 + g * 8);

  f32x4 o[4];
#pragma unroll
  for (int i = 0; i < 4; i++) o[i] = f32x4{0.f, 0.f, 0.f, 0.f};
  float m_run = -1e30f, l_run = 0.f;

  const size_t psBase = (bh * L_ + qrow) * L_;
  const size_t mkBase = ((size_t)b * L_ + qrow) * L_;

  // prefetch preScores tile 0
  float4 psn[4];
#pragma unroll
  for (int i = 0; i < 4; i++)
    psn[i] = *(const float4*)(preScores + psBase + i * 16 + g * 4);

  for (int kt = 0; kt < 16; kt++) {
    const int kv0 = kt * 64;

    // consume prefetched ps, issue next tile's loads immediately
    float4 psc[4];
#pragma unroll
    for (int i = 0; i < 4; i++) psc[i] = psn[i];
    if (kt < 15) {
#pragma unroll
      for (int i = 0; i < 4; i++)
        psn[i] = *(const float4*)(preScores + psBase + kv0 + 64 + i * 16 + g * 4);
    }

    // mask (L3-resident across heads)
    int4 mk[4];
#pragma unroll
    for (int i = 0; i < 4; i++)
      mk[i] = *(const int4*)(maskPAD + mkBase + kv0 + i * 16 + g * 4);

    // S^T = K . Q^T with K fragments straight from L2
    f32x4 st[4];
#pragma unroll
    for (int i = 0; i < 4; i++) st[i] = f32x4{0.f, 0.f, 0.f, 0.f};
#pragma unroll
    for (int s = 0; s < 2; s++) {
#pragma unroll
      for (int i = 0; i < 4; i++) {
        bf16x8 kf = *(const bf16x8*)(Kbh + (size_t)(kv0 + i * 16 + qr) * DK_ + s * 32 + g * 8);
        st[i] = __builtin_amdgcn_mfma_f32_16x16x32_bf16(kf, qf[s], st[i], 0, 0, 0);
      }
    }

    // scale + preScores + mask, write scores, gather row max
    float pmax = -1e30f;
#pragma unroll
    for (int i = 0; i < 4; i++) {
      int ko = i * 16 + g * 4;           // key offset of this lane's 4 values
      float4 sv;
      sv.x = (mk[i].x == 0) ? MASKV : st[i][0] * 0.125f + psc[i].x;
      sv.y = (mk[i].y == 0) ? MASKV : st[i][1] * 0.125f + psc[i].y;
      sv.z = (mk[i].z == 0) ? MASKV : st[i][2] * 0.125f + psc[i].z;
      sv.w = (mk[i].w == 0) ? MASKV : st[i][3] * 0.125f + psc[i].w;
      *(float4*)(scoresOut + psBase + kv0 + ko) = sv;
      st[i][0] = sv.x; st[i][1] = sv.y; st[i][2] = sv.z; st[i][3] = sv.w;
      pmax = fmaxf(pmax, fmaxf(fmaxf(sv.x, sv.y), fmaxf(sv.z, sv.w)));
    }
    pmax = fmaxf(pmax, __shfl_xor(pmax, 16));
    pmax = fmaxf(pmax, __shfl_xor(pmax, 32));
    float mnew = fmaxf(m_run, pmax);
    float fct = __expf(m_run - mnew);
    float psum = 0.f;
#pragma unroll
    for (int i = 0; i < 4; i++) {
      float p0 = __expf(st[i][0] - mnew);
      float p1 = __expf(st[i][1] - mnew);
      float p2 = __expf(st[i][2] - mnew);
      float p3 = __expf(st[i][3] - mnew);
      psum += (p0 + p1) + (p2 + p3);
      s16x4 pw = {f2bf(p0), f2bf(p1), f2bf(p2), f2bf(p3)};
      int c = i * 2 + (g >> 1);          // 16B chunk of this key quad
      *(s16x4*)&lP[wid][qr * 64 + ((c ^ (qr & 7)) << 3) + ((g & 1) << 2)] = pw;
    }
    psum += __shfl_xor(psum, 16);
    psum += __shfl_xor(psum, 32);
    l_run = l_run * fct + psum;
    m_run = mnew;
#pragma unroll
    for (int i = 0; i < 4; i++) {
      o[i][0] *= fct; o[i][1] *= fct; o[i][2] *= fct; o[i][3] *= fct;
    }

    // O^T += Vt_strip . P^T with V fragments straight from L2
#pragma unroll
    for (int s = 0; s < 2; s++) {
      bf16x8 pf = *(const bf16x8*)&lP[wid][qr * 64 + (((s * 4 + g) ^ (qr & 7)) << 3)];
#pragma unroll
      for (int i = 0; i < 4; i++) {
        bf16x8 vf = *(const bf16x8*)(Vbh + (size_t)(i * 16 + qr) * L_ + kv0 + s * 32 + g * 8);
        o[i] = __builtin_amdgcn_mfma_f32_16x16x32_bf16(vf, pf, o[i], 0, 0, 0);
      }
    }
  }

  // normalize and write z_pre [b*L + l][h*64 + d] bf16
  float inv = 1.f / l_run;
  size_t zr = ((size_t)b * L_ + qrow) * FEA_ + (size_t)h * DK_;
#pragma unroll
  for (int i = 0; i < 4; i++) {
    s16x4 zw = {f2bf(o[i][0] * inv), f2bf(o[i][1] * inv),
                f2bf(o[i][2] * inv), f2bf(o[i][3] * inv)};
    *(s16x4*)((unsigned short*)zp + zr + i * 16 + g * 4) = zw;
  }
}

// ---------------------------------------------------------------------------
// Output projection: out[m][n] = sum_k zp[m][k] * Wo[n][k] + bo[n], fp32 out.
// ---------------------------------------------------------------------------
__global__ __launch_bounds__(256) void k_oproj(
    const unsigned short* __restrict__ zp,
    const float* __restrict__ Wo, const float* __restrict__ bo,
    float* __restrict__ out)
{
  __shared__ short lA[128 * 64];
  __shared__ short lB[128 * 64];

  const int tid = threadIdx.x;
  const int lane = tid & 63;
  const int wid = tid >> 6;
  const int wr = wid >> 1, wc = wid & 1;
  const int m0 = blockIdx.x * 128;
  const int n0 = blockIdx.y * 128;
  const int g = lane >> 4, qc = lane & 15;

  f32x4 acc[4][4];
#pragma unroll
  for (int i = 0; i < 4; i++)
#pragma unroll
    for (int j = 0; j < 4; j++) acc[i][j] = f32x4{0.f, 0.f, 0.f, 0.f};

  for (int kt = 0; kt < FEA_; kt += 64) {
#pragma unroll
    for (int i = 0; i < 4; i++) {
      int gg = i * 256 + tid;
      int row = gg >> 3, c = gg & 7;
      bf16x8 av = *(const bf16x8*)(zp + (size_t)(m0 + row) * FEA_ + kt + c * 8);
      *(bf16x8*)&lA[row * 64 + ((c ^ (row & 7)) << 3)] = av;
      const float4* pb = (const float4*)(Wo + (size_t)(n0 + row) * FEA_ + kt + c * 8);
      float4 b0 = pb[0], b1 = pb[1];
      bf16x8 bw;
      bw[0] = f2bf(b0.x); bw[1] = f2bf(b0.y); bw[2] = f2bf(b0.z); bw[3] = f2bf(b0.w);
      bw[4] = f2bf(b1.x); bw[5] = f2bf(b1.y); bw[6] = f2bf(b1.z); bw[7] = f2bf(b1.w);
      *(bf16x8*)&lB[row * 64 + ((c ^ (row & 7)) << 3)] = bw;
    }
    __syncthreads();
#pragma unroll
    for (int s = 0; s < 2; s++) {
      bf16x8 af[4], bfr[4];
#pragma unroll
      for (int i = 0; i < 4; i++) {
        int ar = wr * 64 + i * 16 + qc;
        af[i] = *(const bf16x8*)&lA[ar * 64 + (((s * 4 + g) ^ (ar & 7)) << 3)];
        int br = wc * 64 + i * 16 + qc;
        bfr[i] = *(const bf16x8*)&lB[br * 64 + (((s * 4 + g) ^ (br & 7)) << 3)];
      }
#pragma unroll
      for (int i = 0; i < 4; i++)
#pragma unroll
        for (int j = 0; j < 4; j++)
          acc[i][j] = __builtin_amdgcn_mfma_f32_16x16x32_bf16(af[i], bfr[j], acc[i][j], 0, 0, 0);
    }
    __syncthreads();
  }

  const int cn0 = n0 + wc * 64;
  float bv4[4];
#pragma unroll
  for (int j = 0; j < 4; j++) bv4[j] = bo[cn0 + j * 16 + qc];

#pragma unroll
  for (int i = 0; i < 4; i++) {
    int m = m0 + wr * 64 + i * 16 + g * 4;
#pragma unroll
    for (int j = 0; j < 4; j++) {
      int n = cn0 + j * 16 + qc;
#pragma unroll
      for (int r = 0; r < 4; r++) {
        out[(size_t)(m + r) * FEA_ + n] = acc[i][j][r] + bv4[j];
      }
    }
  }
}

extern "C" void kernel_launch(void* const* d_in, const int* in_sizes, int n_in,
                              void* d_out, int out_size, void* d_ws, size_t ws_size,
                              hipStream_t stream) {
  const float* qx = (const float*)d_in[0];
  const float* kx = (const float*)d_in[1];
  const float* vx = (const float*)d_in[2];
  const float* preScores = (const float*)d_in[3];
  const int* maskPAD = (const int*)d_in[4];
  const float* Wq = (const float*)d_in[5];
  const float* bq = (const float*)d_in[6];
  const float* Wk = (const float*)d_in[7];
  const float* bk = (const float*)d_in[8];
  const float* Wv = (const float*)d_in[9];
  const float* bv = (const float*)d_in[10];
  const float* Wo = (const float*)d_in[11];
  const float* bo = (const float*)d_in[12];

  float* z_out = (float*)d_out;
  float* scores_out = z_out + (size_t)B_ * L_ * FEA_;

  unsigned short* Qb = (unsigned short*)d_ws;
  unsigned short* Kb = Qb + (size_t)B_ * H_ * L_ * DK_;
  unsigned short* Vt = Kb + (size_t)B_ * H_ * L_ * DK_;
  unsigned short* zp = Vt + (size_t)B_ * H_ * L_ * DK_;

  k_proj<<<dim3(32, 6, 3), 256, 0, stream>>>(qx, kx, vx, Wq, bq, Wk, bk, Wv, bv,
                                             Qb, Kb, Vt);
  k_attn<<<dim3(L_ / 64, H_, B_), 256, 0, stream>>>(Qb, Kb, Vt, preScores,
                                                    maskPAD, scores_out, zp);
  k_oproj<<<dim3(32, 6, 1), 256, 0, stream>>>(zp, Wo, bo, z_out);
}

// Round 3
// 215.434 us; speedup vs baseline: 1.2706x; 1.2706x over previous
//
#include <hip/hip_runtime.h>
#include <hip/hip_bf16.h>

#define B_ 4
#define L_ 1024
#define H_ 12
#define DK_ 64
#define FEA_ 768
#define MASKV (-32767.0f)

typedef __attribute__((ext_vector_type(8))) short bf16x8;
typedef __attribute__((ext_vector_type(4))) short s16x4;
typedef __attribute__((ext_vector_type(4))) float f32x4;
typedef unsigned int u32;

__device__ inline short f2bf(float x) {
  union { float f; unsigned u; } v; v.f = x;
  unsigned r = v.u + 0x7fffu + ((v.u >> 16) & 1u);  // RNE
  return (short)(r >> 16);
}

// ---------------------------------------------------------------------------
// QKV projection: out[m][n] = sum_k X[m][k] * W[n][k] + b[n]
// M=4096, N=768, K=768. 128x128 tile, BK=64, 4 waves (2x2), bf16 MFMA.
// Q,K stored [b][h][l][d] bf16; V stored transposed [b][h][d][l] bf16.
// ---------------------------------------------------------------------------
__global__ __launch_bounds__(256) void k_proj(
    const float* __restrict__ qx, const float* __restrict__ kx,
    const float* __restrict__ vx,
    const float* __restrict__ Wq, const float* __restrict__ bq,
    const float* __restrict__ Wk, const float* __restrict__ bk,
    const float* __restrict__ Wv, const float* __restrict__ bv,
    unsigned short* __restrict__ Qb, unsigned short* __restrict__ Kb,
    unsigned short* __restrict__ Vt)
{
  __shared__ short lA[128 * 64];
  __shared__ short lB[128 * 64];

  const int which = blockIdx.z;
  const float* __restrict__ A    = (which == 0) ? qx : (which == 1) ? kx : vx;
  const float* __restrict__ W    = (which == 0) ? Wq : (which == 1) ? Wk : Wv;
  const float* __restrict__ bias = (which == 0) ? bq : (which == 1) ? bk : bv;

  const int tid = threadIdx.x;
  const int lane = tid & 63;
  const int wid = tid >> 6;
  const int wr = wid >> 1, wc = wid & 1;
  const int m0 = blockIdx.x * 128;
  const int n0 = blockIdx.y * 128;
  const int g = lane >> 4, qc = lane & 15;

  f32x4 acc[4][4];
#pragma unroll
  for (int i = 0; i < 4; i++)
#pragma unroll
    for (int j = 0; j < 4; j++) acc[i][j] = f32x4{0.f, 0.f, 0.f, 0.f};

  for (int kt = 0; kt < FEA_; kt += 64) {
#pragma unroll
    for (int i = 0; i < 4; i++) {
      int gg = i * 256 + tid;          // 1024 chunks of 8 elems
      int row = gg >> 3, c = gg & 7;
      const float4* pa = (const float4*)(A + (size_t)(m0 + row) * FEA_ + kt + c * 8);
      float4 a0 = pa[0], a1 = pa[1];
      bf16x8 av;
      av[0] = f2bf(a0.x); av[1] = f2bf(a0.y); av[2] = f2bf(a0.z); av[3] = f2bf(a0.w);
      av[4] = f2bf(a1.x); av[5] = f2bf(a1.y); av[6] = f2bf(a1.z); av[7] = f2bf(a1.w);
      *(bf16x8*)&lA[row * 64 + ((c ^ (row & 7)) << 3)] = av;
      const float4* pb = (const float4*)(W + (size_t)(n0 + row) * FEA_ + kt + c * 8);
      float4 b0 = pb[0], b1 = pb[1];
      bf16x8 bw;
      bw[0] = f2bf(b0.x); bw[1] = f2bf(b0.y); bw[2] = f2bf(b0.z); bw[3] = f2bf(b0.w);
      bw[4] = f2bf(b1.x); bw[5] = f2bf(b1.y); bw[6] = f2bf(b1.z); bw[7] = f2bf(b1.w);
      *(bf16x8*)&lB[row * 64 + ((c ^ (row & 7)) << 3)] = bw;
    }
    __syncthreads();
#pragma unroll
    for (int s = 0; s < 2; s++) {
      bf16x8 af[4], bfr[4];
#pragma unroll
      for (int i = 0; i < 4; i++) {
        int ar = wr * 64 + i * 16 + qc;
        af[i] = *(const bf16x8*)&lA[ar * 64 + (((s * 4 + g) ^ (ar & 7)) << 3)];
        int br = wc * 64 + i * 16 + qc;
        bfr[i] = *(const bf16x8*)&lB[br * 64 + (((s * 4 + g) ^ (br & 7)) << 3)];
      }
#pragma unroll
      for (int i = 0; i < 4; i++)
#pragma unroll
        for (int j = 0; j < 4; j++)
          acc[i][j] = __builtin_amdgcn_mfma_f32_16x16x32_bf16(af[i], bfr[j], acc[i][j], 0, 0, 0);
    }
    __syncthreads();
  }

  const int cn0 = n0 + wc * 64;
  float bv4[4];
#pragma unroll
  for (int j = 0; j < 4; j++) bv4[j] = bias[cn0 + j * 16 + qc];

#pragma unroll
  for (int i = 0; i < 4; i++) {
    int m = m0 + wr * 64 + i * 16 + g * 4;
    int bb = m >> 10;
    int l = m & 1023;
#pragma unroll
    for (int j = 0; j < 4; j++) {
      int n = cn0 + j * 16 + qc;
      int hh = n >> 6, d = n & 63;
#pragma unroll
      for (int r = 0; r < 4; r++) {
        unsigned short v = (unsigned short)f2bf(acc[i][j][r] + bv4[j]);
        if (which == 2) {
          Vt[(((size_t)bb * H_ + hh) * DK_ + d) * L_ + (l + r)] = v;
        } else if (which == 0) {
          Qb[(((size_t)bb * H_ + hh) * L_ + (l + r)) * DK_ + d] = v;
        } else {
          Kb[(((size_t)bb * H_ + hh) * L_ + (l + r)) * DK_ + d] = v;
        }
      }
    }
  }
}

// ---------------------------------------------------------------------------
// Fused attention v3: LDS double-buffer + global_load_lds(16B) staging with
// pre-swizzled per-lane SOURCE addresses (LDS dest linear, read-side XOR
// matches the source permutation). One barrier per kv-tile; staging for tile
// t+1 issued at start of tile t (vmcnt(0)-before-barrier gives it a full tile
// to land). preScores+mask register-prefetched one tile ahead. setprio(1)
// around MFMA clusters. P bounced through wave-private swizzled LDS.
// ---------------------------------------------------------------------------
__global__ __launch_bounds__(256, 3) void k_attn(
    const unsigned short* __restrict__ Qb, const unsigned short* __restrict__ Kb,
    const unsigned short* __restrict__ Vt,
    const float* __restrict__ preScores, const int* __restrict__ maskPAD,
    float* __restrict__ scoresOut, unsigned short* __restrict__ zp)
{
  __shared__ short lK[2][64 * 64];
  __shared__ short lV[2][64 * 64];
  __shared__ short lP[4][16 * 64];

  const int tid = threadIdx.x, lane = tid & 63, wid = tid >> 6;
  const int qt = blockIdx.x, h = blockIdx.y, b = blockIdx.z;
  const int q0 = qt * 64;
  const int g = lane >> 4, qr = lane & 15;
  const int qrow = q0 + wid * 16 + qr;    // global q row in [0,1024)

  const size_t bh = (size_t)b * H_ + h;
  const unsigned short* __restrict__ Kbh = Kb + bh * L_ * DK_;
  const unsigned short* __restrict__ Vbh = Vt + bh * DK_ * L_;

  // staging geometry: wave w covers rows [w*16, w*16+16) in two 8-row groups.
  // lane l -> row r0 + (l>>3), chunk position (l&7); source chunk pre-swizzled
  // so LDS position p of row r holds source chunk p ^ (r&7).
  const int srow = lane >> 3;                 // 0..7 within group
  const int spos = lane & 7;                  // chunk position 0..7

#define STAGE_KV(buf, kv0)                                                     \
  {                                                                            \
    _Pragma("unroll")                                                          \
    for (int i_ = 0; i_ < 2; i_++) {                                           \
      int r0_ = wid * 16 + i_ * 8;                                             \
      int row_ = r0_ + srow;                                                   \
      int cs_ = spos ^ (row_ & 7);                                             \
      __builtin_amdgcn_global_load_lds(                                        \
          (const __attribute__((address_space(1))) u32*)(Kbh +                 \
              (size_t)((kv0) + row_) * DK_ + cs_ * 8),                         \
          (__attribute__((address_space(3))) u32*)&lK[buf][r0_ * 64],          \
          16, 0, 0);                                                           \
      __builtin_amdgcn_global_load_lds(                                        \
          (const __attribute__((address_space(1))) u32*)(Vbh +                 \
              (size_t)row_ * L_ + (kv0) + cs_ * 8),                            \
          (__attribute__((address_space(3))) u32*)&lV[buf][r0_ * 64],          \
          16, 0, 0);                                                           \
    }                                                                          \
  }

  bf16x8 qf[2];
#pragma unroll
  for (int s = 0; s < 2; s++)
    qf[s] = *(const bf16x8*)(Qb + (bh * L_ + qrow) * DK_ + s * 32 + g * 8);

  f32x4 o[4];
#pragma unroll
  for (int i = 0; i < 4; i++) o[i] = f32x4{0.f, 0.f, 0.f, 0.f};
  float m_run = -1e30f, l_run = 0.f;

  const size_t psBase = (bh * L_ + qrow) * L_;
  const size_t mkBase = ((size_t)b * L_ + qrow) * L_;

  // prologue: stage tile 0, prefetch ps/mask tile 0
  STAGE_KV(0, 0);
  float4 psn[4];
  int4 mkn[4];
#pragma unroll
  for (int i = 0; i < 4; i++) {
    psn[i] = *(const float4*)(preScores + psBase + i * 16 + g * 4);
    mkn[i] = *(const int4*)(maskPAD + mkBase + i * 16 + g * 4);
  }
  __syncthreads();

  for (int kt = 0; kt < 16; kt++) {
    const int kv0 = kt * 64;
    const int cur = kt & 1, nxt = cur ^ 1;

    // issue next tile staging first (lands by end-of-tile barrier)
    if (kt < 15) STAGE_KV(nxt, kv0 + 64);

    // rotate ps/mask prefetch
    float4 psc[4]; int4 mkc[4];
#pragma unroll
    for (int i = 0; i < 4; i++) { psc[i] = psn[i]; mkc[i] = mkn[i]; }
    if (kt < 15) {
#pragma unroll
      for (int i = 0; i < 4; i++) {
        psn[i] = *(const float4*)(preScores + psBase + kv0 + 64 + i * 16 + g * 4);
        mkn[i] = *(const int4*)(maskPAD + mkBase + kv0 + 64 + i * 16 + g * 4);
      }
    }

    // S^T = K . Q^T from LDS
    f32x4 st[4];
#pragma unroll
    for (int i = 0; i < 4; i++) st[i] = f32x4{0.f, 0.f, 0.f, 0.f};
    __builtin_amdgcn_s_setprio(1);
#pragma unroll
    for (int s = 0; s < 2; s++) {
#pragma unroll
      for (int i = 0; i < 4; i++) {
        int kr = i * 16 + qr;
        bf16x8 kf = *(const bf16x8*)&lK[cur][kr * 64 + (((s * 4 + g) ^ (kr & 7)) << 3)];
        st[i] = __builtin_amdgcn_mfma_f32_16x16x32_bf16(kf, qf[s], st[i], 0, 0, 0);
      }
    }
    __builtin_amdgcn_s_setprio(0);

    // scale + preScores + mask, write scores, gather row max
    float pmax = -1e30f;
#pragma unroll
    for (int i = 0; i < 4; i++) {
      int ko = i * 16 + g * 4;           // key offset of this lane's 4 values
      float4 sv;
      sv.x = (mkc[i].x == 0) ? MASKV : st[i][0] * 0.125f + psc[i].x;
      sv.y = (mkc[i].y == 0) ? MASKV : st[i][1] * 0.125f + psc[i].y;
      sv.z = (mkc[i].z == 0) ? MASKV : st[i][2] * 0.125f + psc[i].z;
      sv.w = (mkc[i].w == 0) ? MASKV : st[i][3] * 0.125f + psc[i].w;
      *(float4*)(scoresOut + psBase + kv0 + ko) = sv;
      st[i][0] = sv.x; st[i][1] = sv.y; st[i][2] = sv.z; st[i][3] = sv.w;
      pmax = fmaxf(pmax, fmaxf(fmaxf(sv.x, sv.y), fmaxf(sv.z, sv.w)));
    }
    pmax = fmaxf(pmax, __shfl_xor(pmax, 16));
    pmax = fmaxf(pmax, __shfl_xor(pmax, 32));
    float mnew = fmaxf(m_run, pmax);
    float fct = __expf(m_run - mnew);
    float psum = 0.f;
#pragma unroll
    for (int i = 0; i < 4; i++) {
      float p0 = __expf(st[i][0] - mnew);
      float p1 = __expf(st[i][1] - mnew);
      float p2 = __expf(st[i][2] - mnew);
      float p3 = __expf(st[i][3] - mnew);
      psum += (p0 + p1) + (p2 + p3);
      s16x4 pw = {f2bf(p0), f2bf(p1), f2bf(p2), f2bf(p3)};
      int c = i * 2 + (g >> 1);          // 16B chunk of this key quad
      *(s16x4*)&lP[wid][qr * 64 + ((c ^ (qr & 7)) << 3) + ((g & 1) << 2)] = pw;
    }
    psum += __shfl_xor(psum, 16);
    psum += __shfl_xor(psum, 32);
    l_run = l_run * fct + psum;
    m_run = mnew;
#pragma unroll
    for (int i = 0; i < 4; i++) {
      o[i][0] *= fct; o[i][1] *= fct; o[i][2] *= fct; o[i][3] *= fct;
    }

    // O^T += Vt_strip . P^T from LDS
    __builtin_amdgcn_s_setprio(1);
#pragma unroll
    for (int s = 0; s < 2; s++) {
      bf16x8 pf = *(const bf16x8*)&lP[wid][qr * 64 + (((s * 4 + g) ^ (qr & 7)) << 3)];
#pragma unroll
      for (int i = 0; i < 4; i++) {
        int vr = i * 16 + qr;
        bf16x8 vf = *(const bf16x8*)&lV[cur][vr * 64 + (((s * 4 + g) ^ (vr & 7)) << 3)];
        o[i] = __builtin_amdgcn_mfma_f32_16x16x32_bf16(vf, pf, o[i], 0, 0, 0);
      }
    }
    __builtin_amdgcn_s_setprio(0);

    __syncthreads();
  }

  // normalize and write z_pre [b*L + l][h*64 + d] bf16
  float inv = 1.f / l_run;
  size_t zr = ((size_t)b * L_ + qrow) * FEA_ + (size_t)h * DK_;
#pragma unroll
  for (int i = 0; i < 4; i++) {
    s16x4 zw = {f2bf(o[i][0] * inv), f2bf(o[i][1] * inv),
                f2bf(o[i][2] * inv), f2bf(o[i][3] * inv)};
    *(s16x4*)((unsigned short*)zp + zr + i * 16 + g * 4) = zw;
  }
#undef STAGE_KV
}

// ---------------------------------------------------------------------------
// Output projection: out[m][n] = sum_k zp[m][k] * Wo[n][k] + bo[n], fp32 out.
// ---------------------------------------------------------------------------
__global__ __launch_bounds__(256) void k_oproj(
    const unsigned short* __restrict__ zp,
    const float* __restrict__ Wo, const float* __restrict__ bo,
    float* __restrict__ out)
{
  __shared__ short lA[128 * 64];
  __shared__ short lB[128 * 64];

  const int tid = threadIdx.x;
  const int lane = tid & 63;
  const int wid = tid >> 6;
  const int wr = wid >> 1, wc = wid & 1;
  const int m0 = blockIdx.x * 128;
  const int n0 = blockIdx.y * 128;
  const int g = lane >> 4, qc = lane & 15;

  f32x4 acc[4][4];
#pragma unroll
  for (int i = 0; i < 4; i++)
#pragma unroll
    for (int j = 0; j < 4; j++) acc[i][j] = f32x4{0.f, 0.f, 0.f, 0.f};

  for (int kt = 0; kt < FEA_; kt += 64) {
#pragma unroll
    for (int i = 0; i < 4; i++) {
      int gg = i * 256 + tid;
      int row = gg >> 3, c = gg & 7;
      bf16x8 av = *(const bf16x8*)(zp + (size_t)(m0 + row) * FEA_ + kt + c * 8);
      *(bf16x8*)&lA[row * 64 + ((c ^ (row & 7)) << 3)] = av;
      const float4* pb = (const float4*)(Wo + (size_t)(n0 + row) * FEA_ + kt + c * 8);
      float4 b0 = pb[0], b1 = pb[1];
      bf16x8 bw;
      bw[0] = f2bf(b0.x); bw[1] = f2bf(b0.y); bw[2] = f2bf(b0.z); bw[3] = f2bf(b0.w);
      bw[4] = f2bf(b1.x); bw[5] = f2bf(b1.y); bw[6] = f2bf(b1.z); bw[7] = f2bf(b1.w);
      *(bf16x8*)&lB[row * 64 + ((c ^ (row & 7)) << 3)] = bw;
    }
    __syncthreads();
#pragma unroll
    for (int s = 0; s < 2; s++) {
      bf16x8 af[4], bfr[4];
#pragma unroll
      for (int i = 0; i < 4; i++) {
        int ar = wr * 64 + i * 16 + qc;
        af[i] = *(const bf16x8*)&lA[ar * 64 + (((s * 4 + g) ^ (ar & 7)) << 3)];
        int br = wc * 64 + i * 16 + qc;
        bfr[i] = *(const bf16x8*)&lB[br * 64 + (((s * 4 + g) ^ (br & 7)) << 3)];
      }
#pragma unroll
      for (int i = 0; i < 4; i++)
#pragma unroll
        for (int j = 0; j < 4; j++)
          acc[i][j] = __builtin_amdgcn_mfma_f32_16x16x32_bf16(af[i], bfr[j], acc[i][j], 0, 0, 0);
    }
    __syncthreads();
  }

  const int cn0 = n0 + wc * 64;
  float bv4[4];
#pragma unroll
  for (int j = 0; j < 4; j++) bv4[j] = bo[cn0 + j * 16 + qc];

#pragma unroll
  for (int i = 0; i < 4; i++) {
    int m = m0 + wr * 64 + i * 16 + g * 4;
#pragma unroll
    for (int j = 0; j < 4; j++) {
      int n = cn0 + j * 16 + qc;
#pragma unroll
      for (int r = 0; r < 4; r++) {
        out[(size_t)(m + r) * FEA_ + n] = acc[i][j][r] + bv4[j];
      }
    }
  }
}

extern "C" void kernel_launch(void* const* d_in, const int* in_sizes, int n_in,
                              void* d_out, int out_size, void* d_ws, size_t ws_size,
                              hipStream_t stream) {
  const float* qx = (const float*)d_in[0];
  const float* kx = (const float*)d_in[1];
  const float* vx = (const float*)d_in[2];
  const float* preScores = (const float*)d_in[3];
  const int* maskPAD = (const int*)d_in[4];
  const float* Wq = (const float*)d_in[5];
  const float* bq = (const float*)d_in[6];
  const float* Wk = (const float*)d_in[7];
  const float* bk = (const float*)d_in[8];
  const float* Wv = (const float*)d_in[9];
  const float* bv = (const float*)d_in[10];
  const float* Wo = (const float*)d_in[11];
  const float* bo = (const float*)d_in[12];

  float* z_out = (float*)d_out;
  float* scores_out = z_out + (size_t)B_ * L_ * FEA_;

  unsigned short* Qb = (unsigned short*)d_ws;
  unsigned short* Kb = Qb + (size_t)B_ * H_ * L_ * DK_;
  unsigned short* Vt = Kb + (size_t)B_ * H_ * L_ * DK_;
  unsigned short* zp = Vt + (size_t)B_ * H_ * L_ * DK_;

  k_proj<<<dim3(32, 6, 3), 256, 0, stream>>>(qx, kx, vx, Wq, bq, Wk, bk, Wv, bv,
                                             Qb, Kb, Vt);
  k_attn<<<dim3(L_ / 64, H_, B_), 256, 0, stream>>>(Qb, Kb, Vt, preScores,
                                                    maskPAD, scores_out, zp);
  k_oproj<<<dim3(32, 6, 1), 256, 0, stream>>>(zp, Wo, bo, z_out);
}

// Round 4
// 206.645 us; speedup vs baseline: 1.3246x; 1.0425x over previous
//
#include <hip/hip_runtime.h>
#include <hip/hip_bf16.h>

#define B_ 4
#define L_ 1024
#define H_ 12
#define DK_ 64
#define FEA_ 768
#define MASKV (-32767.0f)

typedef __attribute__((ext_vector_type(8))) short bf16x8;
typedef __attribute__((ext_vector_type(4))) short s16x4;
typedef __attribute__((ext_vector_type(4))) float f32x4;
typedef unsigned int u32;

__device__ inline short f2bf(float x) {
  __hip_bfloat16 h = __float2bfloat16(x);   // HW cvt, RNE
  return __builtin_bit_cast(short, h);
}

// ---------------------------------------------------------------------------
// QKV projection: out[m][n] = sum_k X[m][k] * W[n][k] + b[n]
// M=4096, N=768, K=768. 128x128 tile, BK=64, 4 waves (2x2), bf16 MFMA.
// Double-buffered LDS, 1 barrier/k-step, global loads issued before compute.
// Q,K stored [b][h][l][d] bf16; V stored transposed [b][h][d][l] bf16.
// ---------------------------------------------------------------------------
__global__ __launch_bounds__(256) void k_proj(
    const float* __restrict__ qx, const float* __restrict__ kx,
    const float* __restrict__ vx,
    const float* __restrict__ Wq, const float* __restrict__ bq,
    const float* __restrict__ Wk, const float* __restrict__ bk,
    const float* __restrict__ Wv, const float* __restrict__ bv,
    unsigned short* __restrict__ Qb, unsigned short* __restrict__ Kb,
    unsigned short* __restrict__ Vt)
{
  __shared__ short lA[2][128 * 64];
  __shared__ short lB[2][128 * 64];

  const int which = blockIdx.z;
  const float* __restrict__ A    = (which == 0) ? qx : (which == 1) ? kx : vx;
  const float* __restrict__ W    = (which == 0) ? Wq : (which == 1) ? Wk : Wv;
  const float* __restrict__ bias = (which == 0) ? bq : (which == 1) ? bk : bv;

  const int tid = threadIdx.x;
  const int lane = tid & 63;
  const int wid = tid >> 6;
  const int wr = wid >> 1, wc = wid & 1;
  const int m0 = blockIdx.x * 128;
  const int n0 = blockIdx.y * 128;
  const int g = lane >> 4, qc = lane & 15;

  float4 rA[8], rB[8];

#define PROJ_LOAD(ktof)                                                        \
  {                                                                            \
    _Pragma("unroll")                                                          \
    for (int i_ = 0; i_ < 4; i_++) {                                           \
      int gg_ = i_ * 256 + tid;                                                \
      int row_ = gg_ >> 3, c_ = gg_ & 7;                                       \
      const float4* pa_ = (const float4*)(A + (size_t)(m0 + row_) * FEA_ + (ktof) + c_ * 8); \
      rA[i_ * 2] = pa_[0]; rA[i_ * 2 + 1] = pa_[1];                            \
      const float4* pb_ = (const float4*)(W + (size_t)(n0 + row_) * FEA_ + (ktof) + c_ * 8); \
      rB[i_ * 2] = pb_[0]; rB[i_ * 2 + 1] = pb_[1];                            \
    }                                                                          \
  }

#define PROJ_WRITE(buf)                                                        \
  {                                                                            \
    _Pragma("unroll")                                                          \
    for (int i_ = 0; i_ < 4; i_++) {                                           \
      int gg_ = i_ * 256 + tid;                                                \
      int row_ = gg_ >> 3, c_ = gg_ & 7;                                       \
      bf16x8 av_;                                                              \
      av_[0] = f2bf(rA[i_ * 2].x);     av_[1] = f2bf(rA[i_ * 2].y);            \
      av_[2] = f2bf(rA[i_ * 2].z);     av_[3] = f2bf(rA[i_ * 2].w);            \
      av_[4] = f2bf(rA[i_ * 2 + 1].x); av_[5] = f2bf(rA[i_ * 2 + 1].y);        \
      av_[6] = f2bf(rA[i_ * 2 + 1].z); av_[7] = f2bf(rA[i_ * 2 + 1].w);        \
      *(bf16x8*)&lA[buf][row_ * 64 + ((c_ ^ (row_ & 7)) << 3)] = av_;          \
      bf16x8 bw_;                                                              \
      bw_[0] = f2bf(rB[i_ * 2].x);     bw_[1] = f2bf(rB[i_ * 2].y);            \
      bw_[2] = f2bf(rB[i_ * 2].z);     bw_[3] = f2bf(rB[i_ * 2].w);            \
      bw_[4] = f2bf(rB[i_ * 2 + 1].x); bw_[5] = f2bf(rB[i_ * 2 + 1].y);        \
      bw_[6] = f2bf(rB[i_ * 2 + 1].z); bw_[7] = f2bf(rB[i_ * 2 + 1].w);        \
      *(bf16x8*)&lB[buf][row_ * 64 + ((c_ ^ (row_ & 7)) << 3)] = bw_;          \
    }                                                                          \
  }

  f32x4 acc[4][4];
#pragma unroll
  for (int i = 0; i < 4; i++)
#pragma unroll
    for (int j = 0; j < 4; j++) acc[i][j] = f32x4{0.f, 0.f, 0.f, 0.f};

  PROJ_LOAD(0);
  PROJ_WRITE(0);
  __syncthreads();

  for (int kt = 0; kt < 12; kt++) {
    const int cur = kt & 1, nxt = cur ^ 1;
    if (kt < 11) PROJ_LOAD((kt + 1) * 64);
#pragma unroll
    for (int s = 0; s < 2; s++) {
      bf16x8 af[4], bfr[4];
#pragma unroll
      for (int i = 0; i < 4; i++) {
        int ar = wr * 64 + i * 16 + qc;
        af[i] = *(const bf16x8*)&lA[cur][ar * 64 + (((s * 4 + g) ^ (ar & 7)) << 3)];
        int br = wc * 64 + i * 16 + qc;
        bfr[i] = *(const bf16x8*)&lB[cur][br * 64 + (((s * 4 + g) ^ (br & 7)) << 3)];
      }
#pragma unroll
      for (int i = 0; i < 4; i++)
#pragma unroll
        for (int j = 0; j < 4; j++)
          acc[i][j] = __builtin_amdgcn_mfma_f32_16x16x32_bf16(af[i], bfr[j], acc[i][j], 0, 0, 0);
    }
    if (kt < 11) PROJ_WRITE(nxt);
    __syncthreads();
  }

  const int cn0 = n0 + wc * 64;
  float bv4[4];
#pragma unroll
  for (int j = 0; j < 4; j++) bv4[j] = bias[cn0 + j * 16 + qc];

#pragma unroll
  for (int i = 0; i < 4; i++) {
    int m = m0 + wr * 64 + i * 16 + g * 4;
    int bb = m >> 10;
    int l = m & 1023;
#pragma unroll
    for (int j = 0; j < 4; j++) {
      int n = cn0 + j * 16 + qc;
      int hh = n >> 6, d = n & 63;
#pragma unroll
      for (int r = 0; r < 4; r++) {
        unsigned short v = (unsigned short)f2bf(acc[i][j][r] + bv4[j]);
        if (which == 2) {
          Vt[(((size_t)bb * H_ + hh) * DK_ + d) * L_ + (l + r)] = v;
        } else if (which == 0) {
          Qb[(((size_t)bb * H_ + hh) * L_ + (l + r)) * DK_ + d] = v;
        } else {
          Kb[(((size_t)bb * H_ + hh) * L_ + (l + r)) * DK_ + d] = v;
        }
      }
    }
  }
#undef PROJ_LOAD
#undef PROJ_WRITE
}

// ---------------------------------------------------------------------------
// Fused attention v4: counted-vmcnt barrier (T4). STAGE loads pinned oldest
// via sched_barrier(0); s_waitcnt vmcnt(12) + raw s_barrier keeps scores
// stores and ps/mask prefetch loads in flight across the barrier.
// ---------------------------------------------------------------------------
__global__ __launch_bounds__(256, 3) void k_attn(
    const unsigned short* __restrict__ Qb, const unsigned short* __restrict__ Kb,
    const unsigned short* __restrict__ Vt,
    const float* __restrict__ preScores, const int* __restrict__ maskPAD,
    float* __restrict__ scoresOut, unsigned short* __restrict__ zp)
{
  __shared__ short lK[2][64 * 64];
  __shared__ short lV[2][64 * 64];
  __shared__ short lP[4][16 * 64];

  const int tid = threadIdx.x, lane = tid & 63, wid = tid >> 6;
  const int qt = blockIdx.x, h = blockIdx.y, b = blockIdx.z;
  const int q0 = qt * 64;
  const int g = lane >> 4, qr = lane & 15;
  const int qrow = q0 + wid * 16 + qr;    // global q row in [0,1024)

  const size_t bh = (size_t)b * H_ + h;
  const unsigned short* __restrict__ Kbh = Kb + bh * L_ * DK_;
  const unsigned short* __restrict__ Vbh = Vt + bh * DK_ * L_;

  // staging: wave w covers rows [w*16, w*16+16) in two 8-row groups; lane l ->
  // row r0+(l>>3), LDS chunk (l&7); source chunk pre-swizzled (read-side XOR
  // matches). LDS dest linear: base + lane*16B.
  const int srow = lane >> 3;
  const int spos = lane & 7;

#define STAGE_KV(buf, kv0)                                                     \
  {                                                                            \
    _Pragma("unroll")                                                          \
    for (int i_ = 0; i_ < 2; i_++) {                                           \
      int r0_ = wid * 16 + i_ * 8;                                             \
      int row_ = r0_ + srow;                                                   \
      int cs_ = spos ^ (row_ & 7);                                             \
      __builtin_amdgcn_global_load_lds(                                        \
          (const __attribute__((address_space(1))) u32*)(Kbh +                 \
              (size_t)((kv0) + row_) * DK_ + cs_ * 8),                         \
          (__attribute__((address_space(3))) u32*)&lK[buf][r0_ * 64],          \
          16, 0, 0);                                                           \
      __builtin_amdgcn_global_load_lds(                                        \
          (const __attribute__((address_space(1))) u32*)(Vbh +                 \
              (size_t)row_ * L_ + (kv0) + cs_ * 8),                            \
          (__attribute__((address_space(3))) u32*)&lV[buf][r0_ * 64],          \
          16, 0, 0);                                                           \
    }                                                                          \
  }

  bf16x8 qf[2];
#pragma unroll
  for (int s = 0; s < 2; s++)
    qf[s] = *(const bf16x8*)(Qb + (bh * L_ + qrow) * DK_ + s * 32 + g * 8);

  f32x4 o[4];
#pragma unroll
  for (int i = 0; i < 4; i++) o[i] = f32x4{0.f, 0.f, 0.f, 0.f};
  float m_run = -1e30f, l_run = 0.f;

  const size_t psBase = (bh * L_ + qrow) * L_;
  const size_t mkBase = ((size_t)b * L_ + qrow) * L_;

  // prologue: stage tile 0 (pinned oldest), prefetch ps/mask tile 0
  STAGE_KV(0, 0);
  __builtin_amdgcn_sched_barrier(0);
  float4 psn[4];
  int4 mkn[4];
#pragma unroll
  for (int i = 0; i < 4; i++) {
    psn[i] = *(const float4*)(preScores + psBase + i * 16 + g * 4);
    mkn[i] = *(const int4*)(maskPAD + mkBase + i * 16 + g * 4);
  }
  asm volatile("s_waitcnt vmcnt(8)" ::: "memory");
  __builtin_amdgcn_s_barrier();

  for (int kt = 0; kt < 16; kt++) {
    const int kv0 = kt * 64;
    const int cur = kt & 1, nxt = cur ^ 1;

    // issue next tile staging first; pin as oldest outstanding vmem
    if (kt < 15) {
      STAGE_KV(nxt, kv0 + 64);
    }
    __builtin_amdgcn_sched_barrier(0);

    // rotate ps/mask prefetch
    float4 psc[4]; int4 mkc[4];
#pragma unroll
    for (int i = 0; i < 4; i++) { psc[i] = psn[i]; mkc[i] = mkn[i]; }
    if (kt < 15) {
#pragma unroll
      for (int i = 0; i < 4; i++) {
        psn[i] = *(const float4*)(preScores + psBase + kv0 + 64 + i * 16 + g * 4);
        mkn[i] = *(const int4*)(maskPAD + mkBase + kv0 + 64 + i * 16 + g * 4);
      }
    }

    // S^T = K . Q^T from LDS
    f32x4 st[4];
#pragma unroll
    for (int i = 0; i < 4; i++) st[i] = f32x4{0.f, 0.f, 0.f, 0.f};
    __builtin_amdgcn_s_setprio(1);
#pragma unroll
    for (int s = 0; s < 2; s++) {
#pragma unroll
      for (int i = 0; i < 4; i++) {
        int kr = i * 16 + qr;
        bf16x8 kf = *(const bf16x8*)&lK[cur][kr * 64 + (((s * 4 + g) ^ (kr & 7)) << 3)];
        st[i] = __builtin_amdgcn_mfma_f32_16x16x32_bf16(kf, qf[s], st[i], 0, 0, 0);
      }
    }
    __builtin_amdgcn_s_setprio(0);

    // scale + preScores + mask, write scores, gather row max
    float pmax = -1e30f;
#pragma unroll
    for (int i = 0; i < 4; i++) {
      int ko = i * 16 + g * 4;
      float4 sv;
      sv.x = (mkc[i].x == 0) ? MASKV : st[i][0] * 0.125f + psc[i].x;
      sv.y = (mkc[i].y == 0) ? MASKV : st[i][1] * 0.125f + psc[i].y;
      sv.z = (mkc[i].z == 0) ? MASKV : st[i][2] * 0.125f + psc[i].z;
      sv.w = (mkc[i].w == 0) ? MASKV : st[i][3] * 0.125f + psc[i].w;
      *(float4*)(scoresOut + psBase + kv0 + ko) = sv;
      st[i][0] = sv.x; st[i][1] = sv.y; st[i][2] = sv.z; st[i][3] = sv.w;
      pmax = fmaxf(pmax, fmaxf(fmaxf(sv.x, sv.y), fmaxf(sv.z, sv.w)));
    }
    pmax = fmaxf(pmax, __shfl_xor(pmax, 16));
    pmax = fmaxf(pmax, __shfl_xor(pmax, 32));
    float mnew = fmaxf(m_run, pmax);
    float fct = __expf(m_run - mnew);
    float psum = 0.f;
#pragma unroll
    for (int i = 0; i < 4; i++) {
      float p0 = __expf(st[i][0] - mnew);
      float p1 = __expf(st[i][1] - mnew);
      float p2 = __expf(st[i][2] - mnew);
      float p3 = __expf(st[i][3] - mnew);
      psum += (p0 + p1) + (p2 + p3);
      s16x4 pw = {f2bf(p0), f2bf(p1), f2bf(p2), f2bf(p3)};
      int c = i * 2 + (g >> 1);
      *(s16x4*)&lP[wid][qr * 64 + ((c ^ (qr & 7)) << 3) + ((g & 1) << 2)] = pw;
    }
    psum += __shfl_xor(psum, 16);
    psum += __shfl_xor(psum, 32);
    l_run = l_run * fct + psum;
    m_run = mnew;
#pragma unroll
    for (int i = 0; i < 4; i++) {
      o[i][0] *= fct; o[i][1] *= fct; o[i][2] *= fct; o[i][3] *= fct;
    }

    // O^T += Vt_strip . P^T from LDS
    __builtin_amdgcn_s_setprio(1);
#pragma unroll
    for (int s = 0; s < 2; s++) {
      bf16x8 pf = *(const bf16x8*)&lP[wid][qr * 64 + (((s * 4 + g) ^ (qr & 7)) << 3)];
#pragma unroll
      for (int i = 0; i < 4; i++) {
        int vr = i * 16 + qr;
        bf16x8 vf = *(const bf16x8*)&lV[cur][vr * 64 + (((s * 4 + g) ^ (vr & 7)) << 3)];
        o[i] = __builtin_amdgcn_mfma_f32_16x16x32_bf16(vf, pf, o[i], 0, 0, 0);
      }
    }
    __builtin_amdgcn_s_setprio(0);

    // counted barrier: wait only the 4 staging loads (oldest); scores stores
    // (4) and ps/mask prefetch (8) stay in flight.
    asm volatile("s_waitcnt vmcnt(12)" ::: "memory");
    __builtin_amdgcn_s_barrier();
  }

  // normalize and write z_pre [b*L + l][h*64 + d] bf16
  float inv = 1.f / l_run;
  size_t zr = ((size_t)b * L_ + qrow) * FEA_ + (size_t)h * DK_;
#pragma unroll
  for (int i = 0; i < 4; i++) {
    s16x4 zw = {f2bf(o[i][0] * inv), f2bf(o[i][1] * inv),
                f2bf(o[i][2] * inv), f2bf(o[i][3] * inv)};
    *(s16x4*)((unsigned short*)zp + zr + i * 16 + g * 4) = zw;
  }
#undef STAGE_KV
}

// ---------------------------------------------------------------------------
// Output projection: out[m][n] = sum_k zp[m][k] * Wo[n][k] + bo[n], fp32 out.
// Double-buffered LDS, 1 barrier/k-step, loads issued before compute.
// ---------------------------------------------------------------------------
__global__ __launch_bounds__(256) void k_oproj(
    const unsigned short* __restrict__ zp,
    const float* __restrict__ Wo, const float* __restrict__ bo,
    float* __restrict__ out)
{
  __shared__ short lA[2][128 * 64];
  __shared__ short lB[2][128 * 64];

  const int tid = threadIdx.x;
  const int lane = tid & 63;
  const int wid = tid >> 6;
  const int wr = wid >> 1, wc = wid & 1;
  const int m0 = blockIdx.x * 128;
  const int n0 = blockIdx.y * 128;
  const int g = lane >> 4, qc = lane & 15;

  bf16x8 rA[4];
  float4 rB[8];

#define OP_LOAD(ktof)                                                          \
  {                                                                            \
    _Pragma("unroll")                                                          \
    for (int i_ = 0; i_ < 4; i_++) {                                           \
      int gg_ = i_ * 256 + tid;                                                \
      int row_ = gg_ >> 3, c_ = gg_ & 7;                                       \
      rA[i_] = *(const bf16x8*)(zp + (size_t)(m0 + row_) * FEA_ + (ktof) + c_ * 8); \
      const float4* pb_ = (const float4*)(Wo + (size_t)(n0 + row_) * FEA_ + (ktof) + c_ * 8); \
      rB[i_ * 2] = pb_[0]; rB[i_ * 2 + 1] = pb_[1];                            \
    }                                                                          \
  }

#define OP_WRITE(buf)                                                          \
  {                                                                            \
    _Pragma("unroll")                                                          \
    for (int i_ = 0; i_ < 4; i_++) {                                           \
      int gg_ = i_ * 256 + tid;                                                \
      int row_ = gg_ >> 3, c_ = gg_ & 7;                                       \
      *(bf16x8*)&lA[buf][row_ * 64 + ((c_ ^ (row_ & 7)) << 3)] = rA[i_];       \
      bf16x8 bw_;                                                              \
      bw_[0] = f2bf(rB[i_ * 2].x);     bw_[1] = f2bf(rB[i_ * 2].y);            \
      bw_[2] = f2bf(rB[i_ * 2].z);     bw_[3] = f2bf(rB[i_ * 2].w);            \
      bw_[4] = f2bf(rB[i_ * 2 + 1].x); bw_[5] = f2bf(rB[i_ * 2 + 1].y);        \
      bw_[6] = f2bf(rB[i_ * 2 + 1].z); bw_[7] = f2bf(rB[i_ * 2 + 1].w);        \
      *(bf16x8*)&lB[buf][row_ * 64 + ((c_ ^ (row_ & 7)) << 3)] = bw_;          \
    }                                                                          \
  }

  f32x4 acc[4][4];
#pragma unroll
  for (int i = 0; i < 4; i++)
#pragma unroll
    for (int j = 0; j < 4; j++) acc[i][j] = f32x4{0.f, 0.f, 0.f, 0.f};

  OP_LOAD(0);
  OP_WRITE(0);
  __syncthreads();

  for (int kt = 0; kt < 12; kt++) {
    const int cur = kt & 1, nxt = cur ^ 1;
    if (kt < 11) OP_LOAD((kt + 1) * 64);
#pragma unroll
    for (int s = 0; s < 2; s++) {
      bf16x8 af[4], bfr[4];
#pragma unroll
      for (int i = 0; i < 4; i++) {
        int ar = wr * 64 + i * 16 + qc;
        af[i] = *(const bf16x8*)&lA[cur][ar * 64 + (((s * 4 + g) ^ (ar & 7)) << 3)];
        int br = wc * 64 + i * 16 + qc;
        bfr[i] = *(const bf16x8*)&lB[cur][br * 64 + (((s * 4 + g) ^ (br & 7)) << 3)];
      }
#pragma unroll
      for (int i = 0; i < 4; i++)
#pragma unroll
        for (int j = 0; j < 4; j++)
          acc[i][j] = __builtin_amdgcn_mfma_f32_16x16x32_bf16(af[i], bfr[j], acc[i][j], 0, 0, 0);
    }
    if (kt < 11) OP_WRITE(nxt);
    __syncthreads();
  }

  const int cn0 = n0 + wc * 64;
  float bv4[4];
#pragma unroll
  for (int j = 0; j < 4; j++) bv4[j] = bo[cn0 + j * 16 + qc];

#pragma unroll
  for (int i = 0; i < 4; i++) {
    int m = m0 + wr * 64 + i * 16 + g * 4;
#pragma unroll
    for (int j = 0; j < 4; j++) {
      int n = cn0 + j * 16 + qc;
#pragma unroll
      for (int r = 0; r < 4; r++) {
        out[(size_t)(m + r) * FEA_ + n] = acc[i][j][r] + bv4[j];
      }
    }
  }
#undef OP_LOAD
#undef OP_WRITE
}

extern "C" void kernel_launch(void* const* d_in, const int* in_sizes, int n_in,
                              void* d_out, int out_size, void* d_ws, size_t ws_size,
                              hipStream_t stream) {
  const float* qx = (const float*)d_in[0];
  const float* kx = (const float*)d_in[1];
  const float* vx = (const float*)d_in[2];
  const float* preScores = (const float*)d_in[3];
  const int* maskPAD = (const int*)d_in[4];
  const float* Wq = (const float*)d_in[5];
  const float* bq = (const float*)d_in[6];
  const float* Wk = (const float*)d_in[7];
  const float* bk = (const float*)d_in[8];
  const float* Wv = (const float*)d_in[9];
  const float* bv = (const float*)d_in[10];
  const float* Wo = (const float*)d_in[11];
  const float* bo = (const float*)d_in[12];

  float* z_out = (float*)d_out;
  float* scores_out = z_out + (size_t)B_ * L_ * FEA_;

  unsigned short* Qb = (unsigned short*)d_ws;
  unsigned short* Kb = Qb + (size_t)B_ * H_ * L_ * DK_;
  unsigned short* Vt = Kb + (size_t)B_ * H_ * L_ * DK_;
  unsigned short* zp = Vt + (size_t)B_ * H_ * L_ * DK_;

  k_proj<<<dim3(32, 6, 3), 256, 0, stream>>>(qx, kx, vx, Wq, bq, Wk, bk, Wv, bv,
                                             Qb, Kb, Vt);
  k_attn<<<dim3(L_ / 64, H_, B_), 256, 0, stream>>>(Qb, Kb, Vt, preScores,
                                                    maskPAD, scores_out, zp);
  k_oproj<<<dim3(32, 6, 1), 256, 0, stream>>>(zp, Wo, bo, z_out);
}